// Round 1
// baseline (381.393 us; speedup 1.0000x reference)
//
#include <hip/hip_runtime.h>

// Fixed problem dims (from setup_inputs)
static constexpr int B  = 8;
static constexpr int CX = 64;
static constexpr int SX = 8192;   // 128*64
static constexpr int CY = 256;
static constexpr int SY = 2048;   // 64*32
static constexpr int D  = 32;     // Cy/8

// workspace layout (float offsets)
static constexpr int OFF_Q  = 0;                       // [B][SY][D]
static constexpr int OFF_K  = OFF_Q + B * SY * D;      // [B][SY][D]
static constexpr int OFF_V  = OFF_K + B * SY * D;      // [B][SY][CX]  (vT: [b][j][c])
static constexpr int OFF_O  = OFF_V + B * SY * CX;     // [B][CX][SY]  (O: [b][c][i])
static constexpr int OFF_S1 = OFF_O + B * CX * SY;     // [CX] sum
static constexpr int OFF_S2 = OFF_S1 + 64;             // [CX] sumsq
static constexpr int OFF_SC = OFF_S2 + 64;             // [CX] scale
static constexpr int OFF_SH = OFF_SC + 64;             // [CX] shift

// ---------------------------------------------------------------------------
// K1: q/k 1x1 conv.  qT[b][s][d] = sum_c wq[d][c]*y[b][c][s] + bq[d]
// grid 256 (b x 32 s-tiles of 64), block 256 (s = t&63, dgroup = t>>6 -> 8 d's)
// ---------------------------------------------------------------------------
__global__ __launch_bounds__(256) void k_qk(
    const float* __restrict__ y, const float* __restrict__ wq,
    const float* __restrict__ bq, const float* __restrict__ wk,
    const float* __restrict__ bk, float* __restrict__ qT, float* __restrict__ kT)
{
    __shared__ __align__(16) float wlds[CY][68];   // [c][0..31]=wq^T, [c][32..63]=wk^T
    const int t  = threadIdx.x;
    const int b  = blockIdx.x >> 5;
    const int s0 = (blockIdx.x & 31) << 6;

    for (int r = 0; r < 64; ++r) {                 // stage weights transposed
        float v = (r < 32) ? wq[r * CY + t] : wk[(r - 32) * CY + t];
        wlds[t][r] = v;
    }
    __syncthreads();

    const int s  = t & 63;
    const int dg = t >> 6;
    float aq[8], ak[8];
#pragma unroll
    for (int i = 0; i < 8; ++i) { aq[i] = 0.f; ak[i] = 0.f; }

    const float* yb = y + (b * CY) * SY + s0 + s;
#pragma unroll 2
    for (int c = 0; c < CY; ++c) {
        const float yv = yb[c * SY];
        const float4* q4 = reinterpret_cast<const float4*>(&wlds[c][dg * 8]);
        const float4* k4 = reinterpret_cast<const float4*>(&wlds[c][32 + dg * 8]);
        const float4 a0 = q4[0], a1 = q4[1], b0 = k4[0], b1 = k4[1];
        aq[0] += a0.x * yv; aq[1] += a0.y * yv; aq[2] += a0.z * yv; aq[3] += a0.w * yv;
        aq[4] += a1.x * yv; aq[5] += a1.y * yv; aq[6] += a1.z * yv; aq[7] += a1.w * yv;
        ak[0] += b0.x * yv; ak[1] += b0.y * yv; ak[2] += b0.z * yv; ak[3] += b0.w * yv;
        ak[4] += b1.x * yv; ak[5] += b1.y * yv; ak[6] += b1.z * yv; ak[7] += b1.w * yv;
    }
    const int d0   = dg * 8;
    const int base = (b * SY + s0 + s) * D + d0;
    float4 r0, r1;
    r0.x = aq[0] + bq[d0+0]; r0.y = aq[1] + bq[d0+1]; r0.z = aq[2] + bq[d0+2]; r0.w = aq[3] + bq[d0+3];
    r1.x = aq[4] + bq[d0+4]; r1.y = aq[5] + bq[d0+5]; r1.z = aq[6] + bq[d0+6]; r1.w = aq[7] + bq[d0+7];
    *reinterpret_cast<float4*>(qT + base)     = r0;
    *reinterpret_cast<float4*>(qT + base + 4) = r1;
    r0.x = ak[0] + bk[d0+0]; r0.y = ak[1] + bk[d0+1]; r0.z = ak[2] + bk[d0+2]; r0.w = ak[3] + bk[d0+3];
    r1.x = ak[4] + bk[d0+4]; r1.y = ak[5] + bk[d0+5]; r1.z = ak[6] + bk[d0+6]; r1.w = ak[7] + bk[d0+7];
    *reinterpret_cast<float4*>(kT + base)     = r0;
    *reinterpret_cast<float4*>(kT + base + 4) = r1;
}

// ---------------------------------------------------------------------------
// K2: pooled v.  vT[b][jj][c] = sum_ci wv[c][ci] * (sum_{u<4} x[b][ci][4jj+u]) + 4*bv[c]
// grid 256 (b x 32 jj-tiles of 64), block 256 (jj = t&63, cgroup = t>>6 -> 16 c's)
// ---------------------------------------------------------------------------
__global__ __launch_bounds__(256) void k_v(
    const float* __restrict__ x, const float* __restrict__ wv,
    const float* __restrict__ bv, float* __restrict__ vT)
{
    __shared__ __align__(16) float xp[CX][68];
    __shared__ __align__(16) float wt[CX][68];    // wt[cin][cout] = wv[cout][cin]
    const int t   = threadIdx.x;
    const int b   = blockIdx.x >> 5;
    const int jj0 = (blockIdx.x & 31) << 6;
    const int lj  = t & 63;
    const int qd  = t >> 6;

    for (int p = 0; p < 16; ++p) {
        const int flat = p * 256 + t;
        wt[flat & 63][flat >> 6] = wv[flat];
    }
    const float4* x4 = reinterpret_cast<const float4*>(x);
    for (int p = 0; p < 16; ++p) {
        const int ci = p * 4 + qd;
        const float4 v = x4[(b * CX + ci) * (SX / 4) + jj0 + lj];
        xp[ci][lj] = (v.x + v.y) + (v.z + v.w);
    }
    __syncthreads();

    float acc[16];
#pragma unroll
    for (int i = 0; i < 16; ++i) acc[i] = 0.f;
#pragma unroll 2
    for (int ci = 0; ci < 64; ++ci) {
        const float xv = xp[ci][lj];
        const float4* w4 = reinterpret_cast<const float4*>(&wt[ci][qd * 16]);
        const float4 w0 = w4[0], w1 = w4[1], w2 = w4[2], w3 = w4[3];
        acc[0]  += w0.x * xv; acc[1]  += w0.y * xv; acc[2]  += w0.z * xv; acc[3]  += w0.w * xv;
        acc[4]  += w1.x * xv; acc[5]  += w1.y * xv; acc[6]  += w1.z * xv; acc[7]  += w1.w * xv;
        acc[8]  += w2.x * xv; acc[9]  += w2.y * xv; acc[10] += w2.z * xv; acc[11] += w2.w * xv;
        acc[12] += w3.x * xv; acc[13] += w3.y * xv; acc[14] += w3.z * xv; acc[15] += w3.w * xv;
    }
    const int c0 = qd * 16;
    float* dst = vT + (b * SY + jj0 + lj) * CX + c0;
#pragma unroll
    for (int g = 0; g < 4; ++g) {
        float4 o;
        o.x = acc[g*4+0] + 4.f * bv[c0 + g*4+0];
        o.y = acc[g*4+1] + 4.f * bv[c0 + g*4+1];
        o.z = acc[g*4+2] + 4.f * bv[c0 + g*4+2];
        o.w = acc[g*4+3] + 4.f * bv[c0 + g*4+3];
        *reinterpret_cast<float4*>(dst + g * 4) = o;
    }
}

// ---------------------------------------------------------------------------
// K3: flash attention (no-max softmax: |energy| <= ~25 by construction, exp safe)
// grid 256 (b x 32 row-tiles of 64), block 512 = 8 waves.
// lane = row; wave w owns j in [w*256, w*256+256), staged per-wave in LDS tiles of 32.
// Merge: O rows summed in LDS, L summed, normalize; fused BN-stat atomics;
// transposed coalesced write to O[b][c][i].
// ---------------------------------------------------------------------------
__global__ __launch_bounds__(512, 2) void k_attn(
    const float* __restrict__ qT, const float* __restrict__ kT,
    const float* __restrict__ vT, float* __restrict__ O,
    float* __restrict__ s1, float* __restrict__ s2)
{
    __shared__ __align__(16) float4 stage[8 * 768];   // per wave: 256 f4 (k) + 512 f4 (v)
    __shared__ float ldsO[64][69];
    __shared__ float ldsL[8][64];
    __shared__ float invL[64];

    const int t = threadIdx.x;
    const int w = t >> 6, l = t & 63;
    const int b  = blockIdx.x >> 5;
    const int i0 = (blockIdx.x & 31) << 6;
    const int row = i0 + l;

    float4 q4[8];
    const float4* qg = reinterpret_cast<const float4*>(qT) + (b * SY + row) * 8;
#pragma unroll
    for (int i = 0; i < 8; ++i) q4[i] = qg[i];

    float4 Oa[16];
#pragma unroll
    for (int i = 0; i < 16; ++i) Oa[i] = make_float4(0.f, 0.f, 0.f, 0.f);
    float lsum = 0.f;

    float4* kbuf = stage + w * 768;
    float4* vbuf = kbuf + 256;
    const float4* kg = reinterpret_cast<const float4*>(kT) + b * SY * 8;
    const float4* vg = reinterpret_cast<const float4*>(vT) + b * SY * 16;

    for (int tile = 0; tile < 8; ++tile) {
        const int j0 = (w << 8) + (tile << 5);
#pragma unroll
        for (int r = 0; r < 4; ++r) kbuf[(r << 6) + l] = kg[(j0 << 3) + (r << 6) + l];
#pragma unroll
        for (int r = 0; r < 8; ++r) vbuf[(r << 6) + l] = vg[(j0 << 4) + (r << 6) + l];
        asm volatile("s_waitcnt lgkmcnt(0)" ::: "memory");  // per-wave: ds_writes done

#pragma unroll 2
        for (int j = 0; j < 32; ++j) {
            const float4* kr = kbuf + (j << 3);
            float p0 = 0.f, p1 = 0.f, p2 = 0.f, p3 = 0.f;
#pragma unroll
            for (int dd = 0; dd < 8; ++dd) {
                const float4 kv = kr[dd];
                p0 += q4[dd].x * kv.x; p1 += q4[dd].y * kv.y;
                p2 += q4[dd].z * kv.z; p3 += q4[dd].w * kv.w;
            }
            const float p = __expf((p0 + p1) + (p2 + p3));
            lsum += p;
            const float4* vr = vbuf + (j << 4);
#pragma unroll
            for (int cc = 0; cc < 16; ++cc) {
                const float4 vv = vr[cc];
                Oa[cc].x += p * vv.x; Oa[cc].y += p * vv.y;
                Oa[cc].z += p * vv.z; Oa[cc].w += p * vv.w;
            }
        }
        asm volatile("s_waitcnt lgkmcnt(0)" ::: "memory");  // reads drained before restage
    }

    // ---- merge across 8 waves ----
    ldsL[w][l] = lsum;
    for (int ww = 0; ww < 8; ++ww) {
        if (w == ww) {
            float* orow = ldsO[l];
            if (ww == 0) {
#pragma unroll
                for (int cc = 0; cc < 16; ++cc) {
                    orow[4*cc+0] = Oa[cc].x; orow[4*cc+1] = Oa[cc].y;
                    orow[4*cc+2] = Oa[cc].z; orow[4*cc+3] = Oa[cc].w;
                }
            } else {
#pragma unroll
                for (int cc = 0; cc < 16; ++cc) {
                    orow[4*cc+0] += Oa[cc].x; orow[4*cc+1] += Oa[cc].y;
                    orow[4*cc+2] += Oa[cc].z; orow[4*cc+3] += Oa[cc].w;
                }
            }
        }
        __syncthreads();
    }
    if (t < 64) {
        float L = 0.f;
#pragma unroll
        for (int ww = 0; ww < 8; ++ww) L += ldsL[ww][t];
        invL[t] = 1.f / L;
    }
    __syncthreads();

    // fused BN stats (on normalized O, pre-gamma)
    if (t < 64) {
        float sa = 0.f, sq = 0.f;
        for (int r = 0; r < 64; ++r) {
            const float v = ldsO[r][t] * invL[r];
            sa += v; sq += v * v;
        }
        atomicAdd(&s1[t], sa);
        atomicAdd(&s2[t], sq);
    }

    // transposed coalesced write: O[b][c][i0..i0+63]
    float4* Og = reinterpret_cast<float4*>(O);
#pragma unroll
    for (int p = 0; p < 2; ++p) {
        const int f = (p << 9) + t;          // 0..1023
        const int c = f >> 4, i4 = f & 15;
        float4 o;
        o.x = ldsO[i4*4+0][c] * invL[i4*4+0];
        o.y = ldsO[i4*4+1][c] * invL[i4*4+1];
        o.z = ldsO[i4*4+2][c] * invL[i4*4+2];
        o.w = ldsO[i4*4+3][c] * invL[i4*4+3];
        Og[(b * CX + c) * (SY / 4) + (i0 >> 2) + i4] = o;
    }
}

// ---------------------------------------------------------------------------
// K4: BN finalize -> per-channel scale/shift.
// out = x + gamma*O*inv*bn_w + (bn_b - gamma*mean*inv*bn_w)
// ---------------------------------------------------------------------------
__global__ void k_bn(const float* __restrict__ s1, const float* __restrict__ s2,
                     const float* __restrict__ gamma, const float* __restrict__ bn_w,
                     const float* __restrict__ bn_b, float* __restrict__ sc,
                     float* __restrict__ sh)
{
    const int c = threadIdx.x;
    const float g = gamma[0];
    const float invN = 1.f / 16384.f;       // B*SY
    const float mean = s1[c] * invN;
    const float var  = s2[c] * invN - mean * mean;
    const float inv  = rsqrtf(g * g * var + 1e-5f);
    const float scale = g * inv * bn_w[c];
    sc[c] = scale;
    sh[c] = bn_b[c] - mean * scale;
}

// ---------------------------------------------------------------------------
// K5: epilogue.  out[b][c][4jj..4jj+3] = x + O[b][c][jj]*scale[c] + shift[c]
// fully coalesced: gid enumerates [b][c][jj] exactly.
// ---------------------------------------------------------------------------
__global__ __launch_bounds__(256) void k_out(
    const float* __restrict__ x, const float* __restrict__ Obuf,
    const float* __restrict__ sc, const float* __restrict__ sh,
    float* __restrict__ out)
{
    const int gid = blockIdx.x * 256 + threadIdx.x;   // 0 .. B*CX*SY-1
    const int c = (gid >> 11) & 63;
    const float o  = Obuf[gid];
    const float4 xv = reinterpret_cast<const float4*>(x)[gid];
    const float val = o * sc[c] + sh[c];
    float4 r;
    r.x = xv.x + val; r.y = xv.y + val; r.z = xv.z + val; r.w = xv.w + val;
    reinterpret_cast<float4*>(out)[gid] = r;
}

extern "C" void kernel_launch(void* const* d_in, const int* in_sizes, int n_in,
                              void* d_out, int out_size, void* d_ws, size_t ws_size,
                              hipStream_t stream)
{
    (void)in_sizes; (void)n_in; (void)out_size; (void)ws_size;
    const float* x  = (const float*)d_in[0];
    const float* y  = (const float*)d_in[1];
    const float* wq = (const float*)d_in[2];
    const float* bq = (const float*)d_in[3];
    const float* wk = (const float*)d_in[4];
    const float* bk = (const float*)d_in[5];
    const float* wv = (const float*)d_in[6];
    const float* bv = (const float*)d_in[7];
    const float* gm = (const float*)d_in[8];
    const float* bw = (const float*)d_in[9];
    const float* bb = (const float*)d_in[10];

    float* ws  = (float*)d_ws;
    float* qT  = ws + OFF_Q;
    float* kT  = ws + OFF_K;
    float* vT  = ws + OFF_V;
    float* Ob  = ws + OFF_O;
    float* s1p = ws + OFF_S1;
    float* s2p = ws + OFF_S2;
    float* scp = ws + OFF_SC;
    float* shp = ws + OFF_SH;

    hipMemsetAsync(s1p, 0, 128 * sizeof(float), stream);  // zero s1+s2 (ws is poisoned)

    k_qk  <<<256,  256, 0, stream>>>(y, wq, bq, wk, bk, qT, kT);
    k_v   <<<256,  256, 0, stream>>>(x, wv, bv, vT);
    k_attn<<<256,  512, 0, stream>>>(qT, kT, vT, Ob, s1p, s2p);
    k_bn  <<<1,     64, 0, stream>>>(s1p, s2p, gm, bw, bb, scp, shp);
    k_out <<<4096, 256, 0, stream>>>(x, Ob, scp, shp, (float*)d_out);
}

// Round 2
// 195.379 us; speedup vs baseline: 1.9521x; 1.9521x over previous
//
#include <hip/hip_runtime.h>
#include <hip/hip_bf16.h>

typedef __attribute__((ext_vector_type(8))) short short8;
typedef __attribute__((ext_vector_type(4))) float f32x4;
typedef unsigned short ushort_t;
typedef unsigned int uint_t;

// Fixed problem dims
static constexpr int B  = 8;
static constexpr int CX = 64;
static constexpr int SX = 8192;   // 128*64
static constexpr int CY = 256;
static constexpr int SY = 2048;   // 64*32
static constexpr int D  = 32;     // Cy/8

// workspace layout (byte offsets)
static constexpr size_t OFF_Q  = 0;                          // bf16 [B][SY][D]   1 MB
static constexpr size_t OFF_K  = OFF_Q + (size_t)B*SY*D*2;   // bf16 [B][SY][D]   1 MB
static constexpr size_t OFF_V  = OFF_K + (size_t)B*SY*D*2;   // bf16 [B][CX][SY]  2 MB (c-major!)
static constexpr size_t OFF_O  = OFF_V + (size_t)B*CX*SY*2;  // f32  [B][CX][SY]  4 MB
static constexpr size_t OFF_P1 = OFF_O + (size_t)B*CX*SY*4;  // f32  [256][64]
static constexpr size_t OFF_P2 = OFF_P1 + 256*64*4;          // f32  [256][64]
static constexpr size_t OFF_SC = OFF_P2 + 256*64*4;          // f32  [64]
static constexpr size_t OFF_SH = OFF_SC + 64*4;              // f32  [64]

__device__ inline ushort_t f2bf(float f) {                   // RNE f32->bf16
    uint_t u = __builtin_bit_cast(uint_t, f);
    u += 0x7fffu + ((u >> 16) & 1u);
    return (ushort_t)(u >> 16);
}
__device__ inline uint_t pack_bf16(float a, float b) {       // (lo=a, hi=b)
    uint_t ua = __builtin_bit_cast(uint_t, a);
    uint_t ub = __builtin_bit_cast(uint_t, b);
    ua += 0x7fffu + ((ua >> 16) & 1u);
    ub += 0x7fffu + ((ub >> 16) & 1u);
    return (ua >> 16) | (ub & 0xffff0000u);
}

// ---------------------------------------------------------------------------
// K1: q/k 1x1 conv -> bf16 qT/kT [b][s][32]
// grid 256 (b x 32 s-tiles of 64), block 256 (s = t&63, dgroup = t>>6 -> 8 d's)
// ---------------------------------------------------------------------------
__global__ __launch_bounds__(256) void k_qk(
    const float* __restrict__ y, const float* __restrict__ wq,
    const float* __restrict__ bq, const float* __restrict__ wk,
    const float* __restrict__ bk, ushort_t* __restrict__ qT, ushort_t* __restrict__ kT)
{
    __shared__ __align__(16) float wlds[CY][68];   // [c][0..31]=wq^T, [c][32..63]=wk^T
    const int t  = threadIdx.x;
    const int b  = blockIdx.x >> 5;
    const int s0 = (blockIdx.x & 31) << 6;

    for (int r = 0; r < 64; ++r) {
        float v = (r < 32) ? wq[r * CY + t] : wk[(r - 32) * CY + t];
        wlds[t][r] = v;
    }
    __syncthreads();

    const int s  = t & 63;
    const int dg = t >> 6;
    float aq[8], ak[8];
#pragma unroll
    for (int i = 0; i < 8; ++i) { aq[i] = 0.f; ak[i] = 0.f; }

    const float* yb = y + (b * CY) * SY + s0 + s;
#pragma unroll 2
    for (int c = 0; c < CY; ++c) {
        const float yv = yb[c * SY];
        const float4* q4 = reinterpret_cast<const float4*>(&wlds[c][dg * 8]);
        const float4* k4 = reinterpret_cast<const float4*>(&wlds[c][32 + dg * 8]);
        const float4 a0 = q4[0], a1 = q4[1], b0 = k4[0], b1 = k4[1];
        aq[0] += a0.x * yv; aq[1] += a0.y * yv; aq[2] += a0.z * yv; aq[3] += a0.w * yv;
        aq[4] += a1.x * yv; aq[5] += a1.y * yv; aq[6] += a1.z * yv; aq[7] += a1.w * yv;
        ak[0] += b0.x * yv; ak[1] += b0.y * yv; ak[2] += b0.z * yv; ak[3] += b0.w * yv;
        ak[4] += b1.x * yv; ak[5] += b1.y * yv; ak[6] += b1.z * yv; ak[7] += b1.w * yv;
    }
    const int d0   = dg * 8;
    const size_t base = ((size_t)(b * SY + s0 + s)) * D + d0;
    short8 hq, hk;
#pragma unroll
    for (int e = 0; e < 8; ++e) {
        hq[e] = (short)f2bf(aq[e] + bq[d0 + e]);
        hk[e] = (short)f2bf(ak[e] + bk[d0 + e]);
    }
    *reinterpret_cast<short8*>(qT + base) = hq;
    *reinterpret_cast<short8*>(kT + base) = hk;
}

// ---------------------------------------------------------------------------
// K2: pooled v -> bf16 vB [b][c][j]  (c-major rows of 2048)
// grid 256 (b x 32 jj-tiles of 64), block 256 (jj = t&63, cgroup = t>>6 -> 16 c's)
// ---------------------------------------------------------------------------
__global__ __launch_bounds__(256) void k_v(
    const float* __restrict__ x, const float* __restrict__ wv,
    const float* __restrict__ bv, ushort_t* __restrict__ vB)
{
    __shared__ __align__(16) float xp[CX][68];
    __shared__ __align__(16) float wt[CX][68];    // wt[cin][cout] = wv[cout][cin]
    const int t   = threadIdx.x;
    const int b   = blockIdx.x >> 5;
    const int jj0 = (blockIdx.x & 31) << 6;
    const int lj  = t & 63;
    const int qd  = t >> 6;

    for (int p = 0; p < 16; ++p) {
        const int flat = p * 256 + t;
        wt[flat & 63][flat >> 6] = wv[flat];
    }
    const float4* x4 = reinterpret_cast<const float4*>(x);
    for (int p = 0; p < 16; ++p) {
        const int ci = p * 4 + qd;
        const float4 v = x4[(b * CX + ci) * (SX / 4) + jj0 + lj];
        xp[ci][lj] = (v.x + v.y) + (v.z + v.w);
    }
    __syncthreads();

    float acc[16];
#pragma unroll
    for (int i = 0; i < 16; ++i) acc[i] = 0.f;
#pragma unroll 2
    for (int ci = 0; ci < 64; ++ci) {
        const float xv = xp[ci][lj];
        const float4* w4 = reinterpret_cast<const float4*>(&wt[ci][qd * 16]);
        const float4 w0 = w4[0], w1 = w4[1], w2 = w4[2], w3 = w4[3];
        acc[0]  += w0.x * xv; acc[1]  += w0.y * xv; acc[2]  += w0.z * xv; acc[3]  += w0.w * xv;
        acc[4]  += w1.x * xv; acc[5]  += w1.y * xv; acc[6]  += w1.z * xv; acc[7]  += w1.w * xv;
        acc[8]  += w2.x * xv; acc[9]  += w2.y * xv; acc[10] += w2.z * xv; acc[11] += w2.w * xv;
        acc[12] += w3.x * xv; acc[13] += w3.y * xv; acc[14] += w3.z * xv; acc[15] += w3.w * xv;
    }
    const int c0 = qd * 16;
#pragma unroll
    for (int i = 0; i < 16; ++i) {
        vB[((size_t)(b * CX + c0 + i)) * SY + jj0 + lj] = f2bf(acc[i] + 4.f * bv[c0 + i]);
    }
}

// ---------------------------------------------------------------------------
// K3: MFMA flash attention.
// grid 256 (b x 32 i-slabs of 64 rows), block 512 = 8 waves:
//   wave w: i-tile m = w&3 (16 rows), j-half h = w>>2 (1024 js).
// Swapped QK^T: E^T tile = mfma(A=K[jt], B=Q[m]) -> lane holds P for fixed
// i = lane&15, j = 4*(lane>>4)+reg. exp -> pack bf16 pairs -> wave-private
// swizzled P_lds [16][64]; ds_read_b128 A-frags feed PV mfma.
// Epilogue: merge halves + lsum via LDS, BN partials per block, coalesced
// transposed write O[b][c][i].
// ---------------------------------------------------------------------------
__global__ __launch_bounds__(512, 2) void k_attn(
    const ushort_t* __restrict__ qT, const ushort_t* __restrict__ kT,
    const ushort_t* __restrict__ vB, float* __restrict__ O,
    float* __restrict__ part1, float* __restrict__ part2)
{
    __shared__ __align__(16) unsigned char Pl[8][2048];  // per-wave [16 i][64 j] bf16, row 128B, XOR-swz
    __shared__ float Otile[64][68];                      // [c][i] raw O (pre 1/L)
    __shared__ float Lpart[2][64];
    __shared__ float invL[64];

    const int t  = threadIdx.x;
    const int w  = t >> 6, l = t & 63;
    const int g  = l >> 4, li = l & 15;
    const int m  = w & 3,  h  = w >> 2;
    const int b  = blockIdx.x >> 5;
    const int i0 = (blockIdx.x & 31) << 6;

    // Q B-fragment: lane holds Q[i = i0+m*16+li][d = g*8 .. +8)
    const int row = i0 + m * 16 + li;
    const short8 qf = *reinterpret_cast<const short8*>(qT + ((size_t)(b * SY + row)) * D + g * 8);

    const ushort_t* kb = kT + (size_t)b * SY * D;
    const ushort_t* vb = vB + (size_t)b * CX * SY;

    f32x4 acc[4];
#pragma unroll
    for (int n = 0; n < 4; ++n) acc[n] = (f32x4){0.f, 0.f, 0.f, 0.f};
    float lsum = 0.f;

    unsigned char* pbase = &Pl[w][0];
    const int swz = (li & 7) << 4;

    for (int ch = 0; ch < 16; ++ch) {
        const int jbase = h * 1024 + ch * 64;

        // --- QK^T (swapped): 4 E^T tiles of [16 j][16 i] over K=32 ---
        f32x4 d[4];
#pragma unroll
        for (int jt = 0; jt < 4; ++jt) {
            const int jg = jbase + jt * 16 + li;
            const short8 kf = *reinterpret_cast<const short8*>(kb + (size_t)jg * D + g * 8);
            d[jt] = __builtin_amdgcn_mfma_f32_16x16x32_bf16(kf, qf, (f32x4){0.f,0.f,0.f,0.f}, 0, 0, 0);
        }
        // --- exp + pack + stage P (wave-private, no barrier) ---
#pragma unroll
        for (int jt = 0; jt < 4; ++jt) {
            const float p0 = __expf(d[jt][0]);
            const float p1 = __expf(d[jt][1]);
            const float p2 = __expf(d[jt][2]);
            const float p3 = __expf(d[jt][3]);
            lsum += (p0 + p1) + (p2 + p3);
            const int col0 = jt * 32 + g * 8;   // byte col of j = jt*16+4g
            *reinterpret_cast<uint_t*>(pbase + (li << 7) + ( col0      ^ swz)) = pack_bf16(p0, p1);
            *reinterpret_cast<uint_t*>(pbase + (li << 7) + ((col0 + 4) ^ swz)) = pack_bf16(p2, p3);
        }
        // --- PV: O[i][c] += P[i][j] * V[j][c], K=32 per step ---
#pragma unroll
        for (int ks = 0; ks < 2; ++ks) {
            const short8 pf = *reinterpret_cast<const short8*>(
                pbase + (li << 7) + ((ks * 64 + g * 16) ^ swz));
            const int jv = jbase + ks * 32 + g * 8;
#pragma unroll
            for (int n = 0; n < 4; ++n) {
                const short8 vf = *reinterpret_cast<const short8*>(
                    vb + (size_t)(n * 16 + li) * SY + jv);
                acc[n] = __builtin_amdgcn_mfma_f32_16x16x32_bf16(pf, vf, acc[n], 0, 0, 0);
            }
        }
    }

    // ---- epilogue ----
    // lsum: lanes with same li (4 g-groups) hold disjoint j-subsets of row li
    lsum += __shfl_xor(lsum, 16, 64);
    lsum += __shfl_xor(lsum, 32, 64);
    if (l < 16) Lpart[h][m * 16 + l] = lsum;

    if (h == 0) {
#pragma unroll
        for (int n = 0; n < 4; ++n)
#pragma unroll
            for (int r = 0; r < 4; ++r)
                Otile[n * 16 + li][m * 16 + g * 4 + r] = acc[n][r];
    }
    __syncthreads();
    if (h == 1) {
#pragma unroll
        for (int n = 0; n < 4; ++n)
#pragma unroll
            for (int r = 0; r < 4; ++r)
                Otile[n * 16 + li][m * 16 + g * 4 + r] += acc[n][r];
    }
    if (t < 64) invL[t] = 1.f / (Lpart[0][t] + Lpart[1][t]);
    __syncthreads();

    // BN partial sums over this block's 64 i-rows (normalized O, pre-gamma)
    if (t < 64) {
        float sa = 0.f, sq = 0.f;
        for (int i = 0; i < 64; ++i) {
            const float v = Otile[t][i] * invL[i];
            sa += v; sq += v * v;
        }
        part1[blockIdx.x * 64 + t] = sa;
        part2[blockIdx.x * 64 + t] = sq;
    }

    // coalesced transposed write: O[b][c][i0 .. i0+63]
#pragma unroll
    for (int p = 0; p < 2; ++p) {
        const int f  = (p << 9) + t;      // 0..1023
        const int c  = f >> 4, i4 = f & 15;
        float4 o;
        o.x = Otile[c][i4 * 4 + 0] * invL[i4 * 4 + 0];
        o.y = Otile[c][i4 * 4 + 1] * invL[i4 * 4 + 1];
        o.z = Otile[c][i4 * 4 + 2] * invL[i4 * 4 + 2];
        o.w = Otile[c][i4 * 4 + 3] * invL[i4 * 4 + 3];
        reinterpret_cast<float4*>(O)[(size_t)(b * CX + c) * (SY / 4) + (i0 >> 2) + i4] = o;
    }
}

// ---------------------------------------------------------------------------
// K4: reduce 256-block BN partials -> per-channel scale/shift
// ---------------------------------------------------------------------------
__global__ void k_bn(const float* __restrict__ part1, const float* __restrict__ part2,
                     const float* __restrict__ gamma, const float* __restrict__ bn_w,
                     const float* __restrict__ bn_b, float* __restrict__ sc,
                     float* __restrict__ sh)
{
    __shared__ float r1[4][64], r2[4][64];
    const int t = threadIdx.x;
    const int c = t & 63, q = t >> 6;
    float s1 = 0.f, s2 = 0.f;
    for (int n = 0; n < 64; ++n) {
        s1 += part1[(q * 64 + n) * 64 + c];
        s2 += part2[(q * 64 + n) * 64 + c];
    }
    r1[q][c] = s1; r2[q][c] = s2;
    __syncthreads();
    if (t < 64) {
        const float S1 = (r1[0][t] + r1[1][t]) + (r1[2][t] + r1[3][t]);
        const float S2 = (r2[0][t] + r2[1][t]) + (r2[2][t] + r2[3][t]);
        const float g = gamma[0];
        const float invN = 1.f / 16384.f;       // B*SY
        const float mean = S1 * invN;
        const float var  = S2 * invN - mean * mean;
        const float inv  = rsqrtf(g * g * var + 1e-5f);
        const float scale = g * inv * bn_w[t];
        sc[t] = scale;
        sh[t] = bn_b[t] - mean * scale;
    }
}

// ---------------------------------------------------------------------------
// K5: epilogue.  out[b][c][4jj..4jj+3] = x + O[b][c][jj]*scale[c] + shift[c]
// ---------------------------------------------------------------------------
__global__ __launch_bounds__(256) void k_out(
    const float* __restrict__ x, const float* __restrict__ Obuf,
    const float* __restrict__ sc, const float* __restrict__ sh,
    float* __restrict__ out)
{
    const int gid = blockIdx.x * 256 + threadIdx.x;   // 0 .. B*CX*SY-1
    const int c = (gid >> 11) & 63;
    const float o  = Obuf[gid];
    const float4 xv = reinterpret_cast<const float4*>(x)[gid];
    const float val = o * sc[c] + sh[c];
    float4 r;
    r.x = xv.x + val; r.y = xv.y + val; r.z = xv.z + val; r.w = xv.w + val;
    reinterpret_cast<float4*>(out)[gid] = r;
}

extern "C" void kernel_launch(void* const* d_in, const int* in_sizes, int n_in,
                              void* d_out, int out_size, void* d_ws, size_t ws_size,
                              hipStream_t stream)
{
    (void)in_sizes; (void)n_in; (void)out_size; (void)ws_size;
    const float* x  = (const float*)d_in[0];
    const float* y  = (const float*)d_in[1];
    const float* wq = (const float*)d_in[2];
    const float* bq = (const float*)d_in[3];
    const float* wk = (const float*)d_in[4];
    const float* bk = (const float*)d_in[5];
    const float* wv = (const float*)d_in[6];
    const float* bv = (const float*)d_in[7];
    const float* gm = (const float*)d_in[8];
    const float* bw = (const float*)d_in[9];
    const float* bb = (const float*)d_in[10];

    char* ws = (char*)d_ws;
    ushort_t* qT  = (ushort_t*)(ws + OFF_Q);
    ushort_t* kT  = (ushort_t*)(ws + OFF_K);
    ushort_t* vBp = (ushort_t*)(ws + OFF_V);
    float*    Ob  = (float*)(ws + OFF_O);
    float*    p1  = (float*)(ws + OFF_P1);
    float*    p2  = (float*)(ws + OFF_P2);
    float*    scp = (float*)(ws + OFF_SC);
    float*    shp = (float*)(ws + OFF_SH);

    k_qk  <<<256,  256, 0, stream>>>(y, wq, bq, wk, bk, qT, kT);
    k_v   <<<256,  256, 0, stream>>>(x, wv, bv, vBp);
    k_attn<<<256,  512, 0, stream>>>(qT, kT, vBp, Ob, p1, p2);
    k_bn  <<<1,    256, 0, stream>>>(p1, p2, gm, bw, bb, scp, shp);
    k_out <<<4096, 256, 0, stream>>>(x, Ob, scp, shp, (float*)d_out);
}

// Round 4
// 161.524 us; speedup vs baseline: 2.3612x; 1.2096x over previous
//
#include <hip/hip_runtime.h>
#include <hip/hip_bf16.h>

typedef __attribute__((ext_vector_type(8))) short short8;
typedef __attribute__((ext_vector_type(4))) float f32x4;
typedef unsigned short ushort_t;
typedef unsigned int uint_t;

// Fixed problem dims
static constexpr int B  = 8;
static constexpr int CX = 64;
static constexpr int SX = 8192;   // 128*64
static constexpr int CY = 256;
static constexpr int SY = 2048;   // 64*32
static constexpr int D  = 32;     // Cy/8

// workspace layout (byte offsets)
static constexpr size_t OFF_Q  = 0;                          // bf16 [B][SY][D]   1 MB
static constexpr size_t OFF_K  = OFF_Q + (size_t)B*SY*D*2;   // bf16 [B][SY][D]   1 MB
static constexpr size_t OFF_V  = OFF_K + (size_t)B*SY*D*2;   // bf16 [B][CX][SY]  2 MB (c-major!)
static constexpr size_t OFF_O  = OFF_V + (size_t)B*CX*SY*2;  // f32  [B][CX][SY]  4 MB
static constexpr size_t OFF_P1 = OFF_O + (size_t)B*CX*SY*4;  // f32  [256][64]
static constexpr size_t OFF_P2 = OFF_P1 + 256*64*4;          // f32  [256][64]
static constexpr size_t OFF_SC = OFF_P2 + 256*64*4;          // f32  [64]
static constexpr size_t OFF_SH = OFF_SC + 64*4;              // f32  [64]

__device__ inline ushort_t f2bf(float f) {                   // RNE f32->bf16
    uint_t u = __builtin_bit_cast(uint_t, f);
    u += 0x7fffu + ((u >> 16) & 1u);
    return (ushort_t)(u >> 16);
}
__device__ inline uint_t pack_bf16(float a, float b) {       // (lo=a, hi=b)
    uint_t ua = __builtin_bit_cast(uint_t, a);
    uint_t ub = __builtin_bit_cast(uint_t, b);
    ua += 0x7fffu + ((ua >> 16) & 1u);
    ub += 0x7fffu + ((ub >> 16) & 1u);
    return (ua >> 16) | (ub & 0xffff0000u);
}

// ---------------------------------------------------------------------------
// K1: q/k 1x1 conv -> bf16 qT/kT [b][s][32].
// grid 256 (b x 32 s-tiles of 64), block 1024 (16 waves, 50% occ).
// Stage y-tile [256c][64s] f32 + transposed weights [c][64o] in LDS;
// wave w computes outputs o = 4w..4w+3 for s = lane. fp32 math throughout.
// ---------------------------------------------------------------------------
__global__ __launch_bounds__(1024) void k_qk(
    const float* __restrict__ y, const float* __restrict__ wq,
    const float* __restrict__ bq, const float* __restrict__ wk,
    const float* __restrict__ bk, ushort_t* __restrict__ qT, ushort_t* __restrict__ kT)
{
    __shared__ __align__(16) float ylds[256][68];   // y tile [c][s], row 272B (16B-aligned)
    __shared__ __align__(16) float wlds[256][68];   // w^T [c][o]: o<32 wq, o>=32 wk
    const int t  = threadIdx.x;
    const int b  = blockIdx.x >> 5;
    const int s0 = (blockIdx.x & 31) << 6;

    {   // weights transposed, coalesced reads (lanes along c)
        const int c  = t & 255;
        const int rb = (t >> 8) << 4;
#pragma unroll
        for (int i = 0; i < 16; ++i) {
            const int r = rb + i;
            wlds[c][r] = (r < 32) ? wq[r * CY + c] : wk[(r - 32) * CY + c];
        }
    }
    {   // y tile, coalesced float4
        const float4* y4 = reinterpret_cast<const float4*>(y);
#pragma unroll
        for (int p = 0; p < 4; ++p) {
            const int flat = p * 1024 + t;
            const int cc = flat >> 4, s4 = flat & 15;
            const float4 v = y4[(size_t)(b * CY + cc) * (SY / 4) + (s0 >> 2) + s4];
            *reinterpret_cast<float4*>(&ylds[cc][s4 * 4]) = v;
        }
    }
    __syncthreads();

    const int w = t >> 6, s = t & 63;
    float a0 = 0.f, a1 = 0.f, a2 = 0.f, a3 = 0.f;
#pragma unroll 4
    for (int c = 0; c < 256; ++c) {
        const float yv = ylds[c][s];                                   // stride-1: conflict-free
        const float4 wv = *reinterpret_cast<const float4*>(&wlds[c][w * 4]);  // broadcast
        a0 += wv.x * yv; a1 += wv.y * yv; a2 += wv.z * yv; a3 += wv.w * yv;
    }
    const int o = w * 4;
    float b0, b1, b2, b3;
    if (o < 32) { b0 = bq[o]; b1 = bq[o+1]; b2 = bq[o+2]; b3 = bq[o+3]; }
    else        { b0 = bk[o-32]; b1 = bk[o-31]; b2 = bk[o-30]; b3 = bk[o-29]; }

    __syncthreads();   // done reading ylds; reuse as bf16 gather buffer
    ushort_t* qlds = reinterpret_cast<ushort_t*>(&ylds[0][0]);  // [64 s][72 o-pad] ushorts (144B rows)
    {
        uint_t* q32 = reinterpret_cast<uint_t*>(qlds);
        const int base = s * 36 + (o >> 1);          // uint index: (s*72 + o)/2
        q32[base]     = pack_bf16(a0 + b0, a1 + b1);
        q32[base + 1] = pack_bf16(a2 + b2, a3 + b3);
    }
    __syncthreads();

    if (t < 512) {   // coalesced float4 stores of q then k rows
        const int half = t >> 8;                     // 0: q (cols 0..31), 1: k (cols 32..63)
        const int tt = t & 255;
        const int ss = tt >> 2, ch = tt & 3;
        const float4 vv = *reinterpret_cast<const float4*>(&qlds[ss * 72 + half * 32 + ch * 8]);
        ushort_t* dst = half == 0 ? qT : kT;
        reinterpret_cast<float4*>(dst)[(size_t)(b * SY + s0 + ss) * 4 + ch] = vv;
    }
}

// ---------------------------------------------------------------------------
// K2: pooled v -> bf16 vB [b][c][j] (c-major). grid 256, block 1024.
// Pool x in-register during coalesced float4 staging; wave w computes 4 couts.
// ---------------------------------------------------------------------------
__global__ __launch_bounds__(1024) void k_v(
    const float* __restrict__ x, const float* __restrict__ wv,
    const float* __restrict__ bv, ushort_t* __restrict__ vB)
{
    __shared__ __align__(16) float xp[64][68];     // pooled x [cin][j]
    __shared__ __align__(16) float wt[64][68];     // wv^T [cin][cout]
    const int t   = threadIdx.x;
    const int b   = blockIdx.x >> 5;
    const int jj0 = (blockIdx.x & 31) << 6;

#pragma unroll
    for (int p = 0; p < 4; ++p) {                  // weights transposed, coalesced reads
        const int f = p * 1024 + t;
        const int co = f >> 6, ci = f & 63;
        wt[ci][co] = wv[co * 64 + ci];
    }
    {
        const float4* x4 = reinterpret_cast<const float4*>(x);
#pragma unroll
        for (int p = 0; p < 4; ++p) {
            const int f = p * 1024 + t;
            const int ci = f >> 6, j = f & 63;
            const float4 v = x4[(size_t)(b * CX + ci) * (SX / 4) + jj0 + j];
            xp[ci][j] = (v.x + v.y) + (v.z + v.w);
        }
    }
    __syncthreads();

    const int w = t >> 6, j = t & 63;
    float a0 = 0.f, a1 = 0.f, a2 = 0.f, a3 = 0.f;
#pragma unroll 4
    for (int ci = 0; ci < 64; ++ci) {
        const float xv = xp[ci][j];
        const float4 w4 = *reinterpret_cast<const float4*>(&wt[ci][w * 4]);
        a0 += w4.x * xv; a1 += w4.y * xv; a2 += w4.z * xv; a3 += w4.w * xv;
    }
    const int c0 = w * 4;
    const size_t base = (size_t)(b * CX) * SY + jj0 + j;
    vB[base + (size_t)(c0 + 0) * SY] = f2bf(a0 + 4.f * bv[c0 + 0]);
    vB[base + (size_t)(c0 + 1) * SY] = f2bf(a1 + 4.f * bv[c0 + 1]);
    vB[base + (size_t)(c0 + 2) * SY] = f2bf(a2 + 4.f * bv[c0 + 2]);
    vB[base + (size_t)(c0 + 3) * SY] = f2bf(a3 + 4.f * bv[c0 + 3]);
}

// ---------------------------------------------------------------------------
// K3: MFMA flash attention (unchanged from round 2).
// ---------------------------------------------------------------------------
__global__ __launch_bounds__(512, 2) void k_attn(
    const ushort_t* __restrict__ qT, const ushort_t* __restrict__ kT,
    const ushort_t* __restrict__ vB, float* __restrict__ O,
    float* __restrict__ part1, float* __restrict__ part2)
{
    __shared__ __align__(16) unsigned char Pl[8][2048];  // per-wave [16 i][64 j] bf16, row 128B, XOR-swz
    __shared__ float Otile[64][68];                      // [c][i] raw O (pre 1/L)
    __shared__ float Lpart[2][64];
    __shared__ float invL[64];

    const int t  = threadIdx.x;
    const int w  = t >> 6, l = t & 63;
    const int g  = l >> 4, li = l & 15;
    const int m  = w & 3,  h  = w >> 2;
    const int b  = blockIdx.x >> 5;
    const int i0 = (blockIdx.x & 31) << 6;

    const int row = i0 + m * 16 + li;
    const short8 qf = *reinterpret_cast<const short8*>(qT + ((size_t)(b * SY + row)) * D + g * 8);

    const ushort_t* kb = kT + (size_t)b * SY * D;
    const ushort_t* vb = vB + (size_t)b * CX * SY;

    f32x4 acc[4];
#pragma unroll
    for (int n = 0; n < 4; ++n) acc[n] = (f32x4){0.f, 0.f, 0.f, 0.f};
    float lsum = 0.f;

    unsigned char* pbase = &Pl[w][0];
    const int swz = (li & 7) << 4;

    for (int ch = 0; ch < 16; ++ch) {
        const int jbase = h * 1024 + ch * 64;

        f32x4 d[4];
#pragma unroll
        for (int jt = 0; jt < 4; ++jt) {
            const int jg = jbase + jt * 16 + li;
            const short8 kf = *reinterpret_cast<const short8*>(kb + (size_t)jg * D + g * 8);
            d[jt] = __builtin_amdgcn_mfma_f32_16x16x32_bf16(kf, qf, (f32x4){0.f,0.f,0.f,0.f}, 0, 0, 0);
        }
#pragma unroll
        for (int jt = 0; jt < 4; ++jt) {
            const float p0 = __expf(d[jt][0]);
            const float p1 = __expf(d[jt][1]);
            const float p2 = __expf(d[jt][2]);
            const float p3 = __expf(d[jt][3]);
            lsum += (p0 + p1) + (p2 + p3);
            const int col0 = jt * 32 + g * 8;
            *reinterpret_cast<uint_t*>(pbase + (li << 7) + ( col0      ^ swz)) = pack_bf16(p0, p1);
            *reinterpret_cast<uint_t*>(pbase + (li << 7) + ((col0 + 4) ^ swz)) = pack_bf16(p2, p3);
        }
#pragma unroll
        for (int ks = 0; ks < 2; ++ks) {
            const short8 pf = *reinterpret_cast<const short8*>(
                pbase + (li << 7) + ((ks * 64 + g * 16) ^ swz));
            const int jv = jbase + ks * 32 + g * 8;
#pragma unroll
            for (int n = 0; n < 4; ++n) {
                const short8 vf = *reinterpret_cast<const short8*>(
                    vb + (size_t)(n * 16 + li) * SY + jv);
                acc[n] = __builtin_amdgcn_mfma_f32_16x16x32_bf16(pf, vf, acc[n], 0, 0, 0);
            }
        }
    }

    lsum += __shfl_xor(lsum, 16, 64);
    lsum += __shfl_xor(lsum, 32, 64);
    if (l < 16) Lpart[h][m * 16 + l] = lsum;

    if (h == 0) {
#pragma unroll
        for (int n = 0; n < 4; ++n)
#pragma unroll
            for (int r = 0; r < 4; ++r)
                Otile[n * 16 + li][m * 16 + g * 4 + r] = acc[n][r];
    }
    __syncthreads();
    if (h == 1) {
#pragma unroll
        for (int n = 0; n < 4; ++n)
#pragma unroll
            for (int r = 0; r < 4; ++r)
                Otile[n * 16 + li][m * 16 + g * 4 + r] += acc[n][r];
    }
    if (t < 64) invL[t] = 1.f / (Lpart[0][t] + Lpart[1][t]);
    __syncthreads();

    if (t < 64) {
        float sa = 0.f, sq = 0.f;
        for (int i = 0; i < 64; ++i) {
            const float v = Otile[t][i] * invL[i];
            sa += v; sq += v * v;
        }
        part1[blockIdx.x * 64 + t] = sa;
        part2[blockIdx.x * 64 + t] = sq;
    }

#pragma unroll
    for (int p = 0; p < 2; ++p) {
        const int f  = (p << 9) + t;
        const int c  = f >> 4, i4 = f & 15;
        float4 o;
        o.x = Otile[c][i4 * 4 + 0] * invL[i4 * 4 + 0];
        o.y = Otile[c][i4 * 4 + 1] * invL[i4 * 4 + 1];
        o.z = Otile[c][i4 * 4 + 2] * invL[i4 * 4 + 2];
        o.w = Otile[c][i4 * 4 + 3] * invL[i4 * 4 + 3];
        reinterpret_cast<float4*>(O)[(size_t)(b * CX + c) * (SY / 4) + (i0 >> 2) + i4] = o;
    }
}

// ---------------------------------------------------------------------------
// K4: reduce 256-block BN partials -> per-channel scale/shift. block 1024.
// ---------------------------------------------------------------------------
__global__ __launch_bounds__(1024) void k_bn(
    const float* __restrict__ part1, const float* __restrict__ part2,
    const float* __restrict__ gamma, const float* __restrict__ bn_w,
    const float* __restrict__ bn_b, float* __restrict__ sc,
    float* __restrict__ sh)
{
    __shared__ float r1[16][64], r2[16][64];
    const int t = threadIdx.x;
    const int c = t & 63, q = t >> 6;
    float s1 = 0.f, s2 = 0.f;
#pragma unroll
    for (int n = 0; n < 16; ++n) {
        const int row = n * 16 + q;
        s1 += part1[row * 64 + c];
        s2 += part2[row * 64 + c];
    }
    r1[q][c] = s1; r2[q][c] = s2;
    __syncthreads();
    if (t < 64) {
        float S1 = 0.f, S2 = 0.f;
#pragma unroll
        for (int k = 0; k < 16; ++k) { S1 += r1[k][t]; S2 += r2[k][t]; }
        const float g = gamma[0];
        const float invN = 1.f / 16384.f;       // B*SY
        const float mean = S1 * invN;
        const float var  = S2 * invN - mean * mean;
        const float inv  = rsqrtf(g * g * var + 1e-5f);
        const float scale = g * inv * bn_w[t];
        sc[t] = scale;
        sh[t] = bn_b[t] - mean * scale;
    }
}

// ---------------------------------------------------------------------------
// K5: epilogue.  out[b][c][4jj..4jj+3] = x + O[b][c][jj]*scale[c] + shift[c]
// ---------------------------------------------------------------------------
__global__ __launch_bounds__(256) void k_out(
    const float* __restrict__ x, const float* __restrict__ Obuf,
    const float* __restrict__ sc, const float* __restrict__ sh,
    float* __restrict__ out)
{
    const int gid = blockIdx.x * 256 + threadIdx.x;   // 0 .. B*CX*SY-1
    const int c = (gid >> 11) & 63;
    const float o  = Obuf[gid];
    const float4 xv = reinterpret_cast<const float4*>(x)[gid];
    const float val = o * sc[c] + sh[c];
    float4 r;
    r.x = xv.x + val; r.y = xv.y + val; r.z = xv.z + val; r.w = xv.w + val;
    reinterpret_cast<float4*>(out)[gid] = r;
}

extern "C" void kernel_launch(void* const* d_in, const int* in_sizes, int n_in,
                              void* d_out, int out_size, void* d_ws, size_t ws_size,
                              hipStream_t stream)
{
    (void)in_sizes; (void)n_in; (void)out_size; (void)ws_size;
    const float* x  = (const float*)d_in[0];
    const float* y  = (const float*)d_in[1];
    const float* wq = (const float*)d_in[2];
    const float* bq = (const float*)d_in[3];
    const float* wk = (const float*)d_in[4];
    const float* bk = (const float*)d_in[5];
    const float* wv = (const float*)d_in[6];
    const float* bv = (const float*)d_in[7];
    const float* gm = (const float*)d_in[8];
    const float* bw = (const float*)d_in[9];
    const float* bb = (const float*)d_in[10];

    char* ws = (char*)d_ws;
    ushort_t* qT  = (ushort_t*)(ws + OFF_Q);
    ushort_t* kT  = (ushort_t*)(ws + OFF_K);
    ushort_t* vBp = (ushort_t*)(ws + OFF_V);
    float*    Ob  = (float*)(ws + OFF_O);
    float*    p1  = (float*)(ws + OFF_P1);
    float*    p2  = (float*)(ws + OFF_P2);
    float*    scp = (float*)(ws + OFF_SC);
    float*    shp = (float*)(ws + OFF_SH);

    k_qk  <<<256, 1024, 0, stream>>>(y, wq, bq, wk, bk, qT, kT);
    k_v   <<<256, 1024, 0, stream>>>(x, wv, bv, vBp);
    k_attn<<<256,  512, 0, stream>>>(qT, kT, vBp, Ob, p1, p2);
    k_bn  <<<1,   1024, 0, stream>>>(p1, p2, gm, bw, bb, scp, shp);
    k_out <<<4096, 256, 0, stream>>>(x, Ob, scp, shp, (float*)d_out);
}

// Round 6
// 142.547 us; speedup vs baseline: 2.6756x; 1.1331x over previous
//
#include <hip/hip_runtime.h>
#include <hip/hip_bf16.h>

typedef __attribute__((ext_vector_type(8))) short short8;
typedef __attribute__((ext_vector_type(4))) float f32x4;
typedef unsigned short ushort_t;
typedef unsigned int uint_t;

// Fixed problem dims
static constexpr int B  = 8;
static constexpr int CX = 64;
static constexpr int SX = 8192;   // 128*64
static constexpr int CY = 256;
static constexpr int SY = 2048;   // 64*32
static constexpr int D  = 32;     // Cy/8

// workspace layout (byte offsets)
static constexpr size_t OFF_Q  = 0;                          // bf16 [B][SY][D]   1 MB
static constexpr size_t OFF_K  = OFF_Q + (size_t)B*SY*D*2;   // bf16 [B][SY][D]   1 MB
static constexpr size_t OFF_V  = OFF_K + (size_t)B*SY*D*2;   // bf16 [B][CX][SY]  2 MB (c-major!)
static constexpr size_t OFF_O  = OFF_V + (size_t)B*CX*SY*2;  // f32  [B][CX][SY]  4 MB
static constexpr size_t OFF_P1 = OFF_O + (size_t)B*CX*SY*4;  // f32  [256][64]
static constexpr size_t OFF_P2 = OFF_P1 + 256*64*4;          // f32  [256][64]
static constexpr size_t OFF_SC = OFF_P2 + 256*64*4;          // f32  [64]
static constexpr size_t OFF_SH = OFF_SC + 64*4;              // f32  [64]

__device__ inline ushort_t f2bf(float f) {                   // RNE f32->bf16
    uint_t u = __builtin_bit_cast(uint_t, f);
    u += 0x7fffu + ((u >> 16) & 1u);
    return (ushort_t)(u >> 16);
}
__device__ inline uint_t pack_bf16(float a, float b) {       // (lo=a, hi=b)
    uint_t ua = __builtin_bit_cast(uint_t, a);
    uint_t ub = __builtin_bit_cast(uint_t, b);
    ua += 0x7fffu + ((ua >> 16) & 1u);
    ub += 0x7fffu + ((ub >> 16) & 1u);
    return (ua >> 16) | (ub & 0xffff0000u);
}

// ---------------------------------------------------------------------------
// K1: q/k 1x1 conv -> bf16 qT/kT [b][s][32].
// ---------------------------------------------------------------------------
__global__ __launch_bounds__(1024) void k_qk(
    const float* __restrict__ y, const float* __restrict__ wq,
    const float* __restrict__ bq, const float* __restrict__ wk,
    const float* __restrict__ bk, ushort_t* __restrict__ qT, ushort_t* __restrict__ kT)
{
    __shared__ __align__(16) float ylds[256][68];
    __shared__ __align__(16) float wlds[256][68];
    const int t  = threadIdx.x;
    const int b  = blockIdx.x >> 5;
    const int s0 = (blockIdx.x & 31) << 6;

    {
        const int c  = t & 255;
        const int rb = (t >> 8) << 4;
#pragma unroll
        for (int i = 0; i < 16; ++i) {
            const int r = rb + i;
            wlds[c][r] = (r < 32) ? wq[r * CY + c] : wk[(r - 32) * CY + c];
        }
    }
    {
        const float4* y4 = reinterpret_cast<const float4*>(y);
#pragma unroll
        for (int p = 0; p < 4; ++p) {
            const int flat = p * 1024 + t;
            const int cc = flat >> 4, s4 = flat & 15;
            const float4 v = y4[(size_t)(b * CY + cc) * (SY / 4) + (s0 >> 2) + s4];
            *reinterpret_cast<float4*>(&ylds[cc][s4 * 4]) = v;
        }
    }
    __syncthreads();

    const int w = t >> 6, s = t & 63;
    float a0 = 0.f, a1 = 0.f, a2 = 0.f, a3 = 0.f;
#pragma unroll 4
    for (int c = 0; c < 256; ++c) {
        const float yv = ylds[c][s];
        const float4 wv = *reinterpret_cast<const float4*>(&wlds[c][w * 4]);
        a0 += wv.x * yv; a1 += wv.y * yv; a2 += wv.z * yv; a3 += wv.w * yv;
    }
    const int o = w * 4;
    float b0, b1, b2, b3;
    if (o < 32) { b0 = bq[o]; b1 = bq[o+1]; b2 = bq[o+2]; b3 = bq[o+3]; }
    else        { b0 = bk[o-32]; b1 = bk[o-31]; b2 = bk[o-30]; b3 = bk[o-29]; }

    __syncthreads();
    ushort_t* qlds = reinterpret_cast<ushort_t*>(&ylds[0][0]);  // [64 s][72 o-pad]
    {
        uint_t* q32 = reinterpret_cast<uint_t*>(qlds);
        const int base = s * 36 + (o >> 1);
        q32[base]     = pack_bf16(a0 + b0, a1 + b1);
        q32[base + 1] = pack_bf16(a2 + b2, a3 + b3);
    }
    __syncthreads();

    if (t < 512) {
        const int half = t >> 8;
        const int tt = t & 255;
        const int ss = tt >> 2, ch = tt & 3;
        const float4 vv = *reinterpret_cast<const float4*>(&qlds[ss * 72 + half * 32 + ch * 8]);
        ushort_t* dst = half == 0 ? qT : kT;
        reinterpret_cast<float4*>(dst)[(size_t)(b * SY + s0 + ss) * 4 + ch] = vv;
    }
}

// ---------------------------------------------------------------------------
// K2: pooled v -> bf16 vB [b][c][j] (c-major). grid 256, block 1024.
// ---------------------------------------------------------------------------
__global__ __launch_bounds__(1024) void k_v(
    const float* __restrict__ x, const float* __restrict__ wv,
    const float* __restrict__ bv, ushort_t* __restrict__ vB)
{
    __shared__ __align__(16) float xp[64][68];
    __shared__ __align__(16) float wt[64][68];
    const int t   = threadIdx.x;
    const int b   = blockIdx.x >> 5;
    const int jj0 = (blockIdx.x & 31) << 6;

#pragma unroll
    for (int p = 0; p < 4; ++p) {
        const int f = p * 1024 + t;
        const int co = f >> 6, ci = f & 63;
        wt[ci][co] = wv[co * 64 + ci];
    }
    {
        const float4* x4 = reinterpret_cast<const float4*>(x);
#pragma unroll
        for (int p = 0; p < 4; ++p) {
            const int f = p * 1024 + t;
            const int ci = f >> 6, j = f & 63;
            const float4 v = x4[(size_t)(b * CX + ci) * (SX / 4) + jj0 + j];
            xp[ci][j] = (v.x + v.y) + (v.z + v.w);
        }
    }
    __syncthreads();

    const int w = t >> 6, j = t & 63;
    float a0 = 0.f, a1 = 0.f, a2 = 0.f, a3 = 0.f;
#pragma unroll 4
    for (int ci = 0; ci < 64; ++ci) {
        const float xv = xp[ci][j];
        const float4 w4 = *reinterpret_cast<const float4*>(&wt[ci][w * 4]);
        a0 += w4.x * xv; a1 += w4.y * xv; a2 += w4.z * xv; a3 += w4.w * xv;
    }
    const int c0 = w * 4;
    const size_t base = (size_t)(b * CX) * SY + jj0 + j;
    vB[base + (size_t)(c0 + 0) * SY] = f2bf(a0 + 4.f * bv[c0 + 0]);
    vB[base + (size_t)(c0 + 1) * SY] = f2bf(a1 + 4.f * bv[c0 + 1]);
    vB[base + (size_t)(c0 + 2) * SY] = f2bf(a2 + 4.f * bv[c0 + 2]);
    vB[base + (size_t)(c0 + 3) * SY] = f2bf(a3 + 4.f * bv[c0 + 3]);
}

// ---------------------------------------------------------------------------
// K3 v3: lockstep chunked MFMA flash attention.
// grid 256 (b x 32 slabs of 64 i-rows), block 1024 = 16 waves (4/SIMD, 50% occ).
// j processed in 16 chunks of 128; K (8KB) + V (16KB, source-swizzled) are
// reg-staged double-buffered; P [64i][128j] bf16 XOR-swizzled in LDS.
// QK role: wave=(jtt=w>>1, h=w&1): 1 kf read, 2 mfmas (m=2h,2h+1), 8 exps/lane.
// PV role: wave=(n=w&3, ks=w>>2): 1 vf + 4 pf reads, 4 mfmas -> partial O(m,n;ks).
// Epilogue: 4-round ks-merge into Otile, invL, BN partials, coalesced O write.
// ---------------------------------------------------------------------------
__global__ __launch_bounds__(1024) void k_attn(
    const ushort_t* __restrict__ qT, const ushort_t* __restrict__ kT,
    const ushort_t* __restrict__ vB, float* __restrict__ O,
    float* __restrict__ part1, float* __restrict__ part2)
{
    __shared__ __align__(16) unsigned char smem[65536];
    // main-loop layout: K dbuf [2][8192] | V dbuf [2][16384] | P [16384]
    unsigned char* Kb0 = smem;
    unsigned char* Kb1 = smem + 8192;
    unsigned char* Vb0 = smem + 16384;
    unsigned char* Vb1 = smem + 32768;
    unsigned char* Pl  = smem + 49152;
    // epilogue overlay (post-loop, barrier-separated)
    float* Otile = reinterpret_cast<float*>(smem);
    float* Lpart = reinterpret_cast<float*>(smem + 17408);
    float* invL  = reinterpret_cast<float*>(smem + 19456);

    const int t  = threadIdx.x;
    const int w  = t >> 6, l = t & 63;
    const int g  = l >> 4, li = l & 15;
    const int b  = blockIdx.x >> 5;
    const int i0 = (blockIdx.x & 31) << 6;

    const int jtt = w >> 1, h = w & 1;     // QK role
    const int n   = w & 3,  ks = w >> 2;   // PV role
    const int m0  = 2 * h, m1 = 2 * h + 1;

    const ushort_t* kb = kT + (size_t)b * SY * D;
    const ushort_t* vb = vB + (size_t)b * CX * SY;

    const short8 qf0 = *reinterpret_cast<const short8*>(
        qT + ((size_t)(b * SY + i0 + m0 * 16 + li)) * D + g * 8);
    const short8 qf1 = *reinterpret_cast<const short8*>(
        qT + ((size_t)(b * SY + i0 + m1 * 16 + li)) * D + g * 8);

    const int koff = w * 1024 + l * 16;                 // waves 0..7: K flat slice
    const int vc = w * 4 + g;                           // V: c-row
    const int vldso = vc * 256 + li * 16;               // V LDS offset (linear)
    const unsigned char* kgb = reinterpret_cast<const unsigned char*>(kb);
    const unsigned char* vgb = reinterpret_cast<const unsigned char*>(vb)
                             + (size_t)vc * (SY * 2) + ((li ^ (vc & 7)) * 16);

    f32x4 acc[4];
#pragma unroll
    for (int m = 0; m < 4; ++m) acc[m] = (f32x4){0.f, 0.f, 0.f, 0.f};
    float lsum0 = 0.f, lsum1 = 0.f;

    const int swzP = (li & 7) << 4;

    // prologue: stage chunk 0 into buf0
    {
        short8 kr, vr;
        if (w < 8) kr = *reinterpret_cast<const short8*>(kgb + koff);
        vr = *reinterpret_cast<const short8*>(vgb);
        if (w < 8) *reinterpret_cast<short8*>(Kb0 + koff) = kr;
        *reinterpret_cast<short8*>(Vb0 + vldso) = vr;
    }
    __syncthreads();

    for (int ch = 0; ch < 16; ++ch) {
        unsigned char* Kc = (ch & 1) ? Kb1 : Kb0;
        unsigned char* Vc = (ch & 1) ? Vb1 : Vb0;
        unsigned char* Kn = (ch & 1) ? Kb0 : Kb1;
        unsigned char* Vn = (ch & 1) ? Vb0 : Vb1;

        // issue next-chunk global loads early (latency hides under compute)
        short8 kr, vr;
        if (ch < 15) {
            if (w < 8) kr = *reinterpret_cast<const short8*>(kgb + (size_t)(ch + 1) * 8192 + koff);
            vr = *reinterpret_cast<const short8*>(vgb + (size_t)(ch + 1) * 256);
        }

        // --- QK: one kf, two mfmas ---
        const short8 kf = *reinterpret_cast<const short8*>(Kc + (jtt * 16 + li) * 64 + g * 16);
        const f32x4 d0 = __builtin_amdgcn_mfma_f32_16x16x32_bf16(kf, qf0, (f32x4){0.f,0.f,0.f,0.f}, 0, 0, 0);
        const f32x4 d1 = __builtin_amdgcn_mfma_f32_16x16x32_bf16(kf, qf1, (f32x4){0.f,0.f,0.f,0.f}, 0, 0, 0);

        // --- exp + pack + P write (rows m0/m1, cols jtt-subtile) ---
        {
            const float e0 = __expf(d0[0]), e1 = __expf(d0[1]);
            const float e2 = __expf(d0[2]), e3 = __expf(d0[3]);
            lsum0 += (e0 + e1) + (e2 + e3);
            uint2 pw; pw.x = pack_bf16(e0, e1); pw.y = pack_bf16(e2, e3);
            *reinterpret_cast<uint2*>(Pl + (m0 * 16 + li) * 256 + ((jtt * 32 + g * 8) ^ swzP)) = pw;
        }
        {
            const float e0 = __expf(d1[0]), e1 = __expf(d1[1]);
            const float e2 = __expf(d1[2]), e3 = __expf(d1[3]);
            lsum1 += (e0 + e1) + (e2 + e3);
            uint2 pw; pw.x = pack_bf16(e0, e1); pw.y = pack_bf16(e2, e3);
            *reinterpret_cast<uint2*>(Pl + (m1 * 16 + li) * 256 + ((jtt * 32 + g * 8) ^ swzP)) = pw;
        }
        __syncthreads();   // P published

        // --- PV: partial O(m, n; ks) ---
        const short8 vf = *reinterpret_cast<const short8*>(
            Vc + (n * 16 + li) * 256 + ((ks * 64 + g * 16) ^ ((li & 7) << 4)));
#pragma unroll
        for (int m = 0; m < 4; ++m) {
            const short8 pf = *reinterpret_cast<const short8*>(
                Pl + (m * 16 + li) * 256 + ((ks * 64 + g * 16) ^ swzP));
            acc[m] = __builtin_amdgcn_mfma_f32_16x16x32_bf16(pf, vf, acc[m], 0, 0, 0);
        }

        // write staged regs into next buffers
        if (ch < 15) {
            if (w < 8) *reinterpret_cast<short8*>(Kn + koff) = kr;
            *reinterpret_cast<short8*>(Vn + vldso) = vr;
        }
        __syncthreads();   // next buffers ready; P free for overwrite
    }

    // ---- epilogue ----
    lsum0 += __shfl_xor(lsum0, 16, 64);
    lsum0 += __shfl_xor(lsum0, 32, 64);
    lsum1 += __shfl_xor(lsum1, 16, 64);
    lsum1 += __shfl_xor(lsum1, 32, 64);
    if (l < 16) {
        Lpart[jtt * 64 + m0 * 16 + l] = lsum0;
        Lpart[jtt * 64 + m1 * 16 + l] = lsum1;
    }
    if (ks == 0) {
#pragma unroll
        for (int m = 0; m < 4; ++m) {
            float4 v = make_float4(acc[m][0], acc[m][1], acc[m][2], acc[m][3]);
            *reinterpret_cast<float4*>(&Otile[(n * 16 + li) * 68 + m * 16 + g * 4]) = v;
        }
    }
    __syncthreads();
    if (t < 64) {
        float L = 0.f;
#pragma unroll
        for (int jj = 0; jj < 8; ++jj) L += Lpart[jj * 64 + t];
        invL[t] = 1.f / L;
    }
    if (ks == 1) {
#pragma unroll
        for (int m = 0; m < 4; ++m) {
            float4* p = reinterpret_cast<float4*>(&Otile[(n * 16 + li) * 68 + m * 16 + g * 4]);
            float4 v = *p;
            v.x += acc[m][0]; v.y += acc[m][1]; v.z += acc[m][2]; v.w += acc[m][3];
            *p = v;
        }
    }
    __syncthreads();
    if (ks == 2) {
#pragma unroll
        for (int m = 0; m < 4; ++m) {
            float4* p = reinterpret_cast<float4*>(&Otile[(n * 16 + li) * 68 + m * 16 + g * 4]);
            float4 v = *p;
            v.x += acc[m][0]; v.y += acc[m][1]; v.z += acc[m][2]; v.w += acc[m][3];
            *p = v;
        }
    }
    __syncthreads();
    if (ks == 3) {
#pragma unroll
        for (int m = 0; m < 4; ++m) {
            float4* p = reinterpret_cast<float4*>(&Otile[(n * 16 + li) * 68 + m * 16 + g * 4]);
            float4 v = *p;
            v.x += acc[m][0]; v.y += acc[m][1]; v.z += acc[m][2]; v.w += acc[m][3];
            *p = v;
        }
    }
    __syncthreads();

    if (t < 64) {
        float sa = 0.f, sq = 0.f;
        for (int i = 0; i < 64; ++i) {
            const float v = Otile[t * 68 + i] * invL[i];
            sa += v; sq += v * v;
        }
        part1[blockIdx.x * 64 + t] = sa;
        part2[blockIdx.x * 64 + t] = sq;
    }

    {
        const int c = t >> 4, i4 = t & 15;
        float4 o;
        o.x = Otile[c * 68 + i4 * 4 + 0] * invL[i4 * 4 + 0];
        o.y = Otile[c * 68 + i4 * 4 + 1] * invL[i4 * 4 + 1];
        o.z = Otile[c * 68 + i4 * 4 + 2] * invL[i4 * 4 + 2];
        o.w = Otile[c * 68 + i4 * 4 + 3] * invL[i4 * 4 + 3];
        reinterpret_cast<float4*>(O)[(size_t)(b * CX + c) * (SY / 4) + (i0 >> 2) + i4] = o;
    }
}

// ---------------------------------------------------------------------------
// K4: reduce 256-block BN partials -> per-channel scale/shift. block 1024.
// ---------------------------------------------------------------------------
__global__ __launch_bounds__(1024) void k_bn(
    const float* __restrict__ part1, const float* __restrict__ part2,
    const float* __restrict__ gamma, const float* __restrict__ bn_w,
    const float* __restrict__ bn_b, float* __restrict__ sc,
    float* __restrict__ sh)
{
    __shared__ float r1[16][64], r2[16][64];
    const int t = threadIdx.x;
    const int c = t & 63, q = t >> 6;
    float s1 = 0.f, s2 = 0.f;
#pragma unroll
    for (int n = 0; n < 16; ++n) {
        const int row = n * 16 + q;
        s1 += part1[row * 64 + c];
        s2 += part2[row * 64 + c];
    }
    r1[q][c] = s1; r2[q][c] = s2;
    __syncthreads();
    if (t < 64) {
        float S1 = 0.f, S2 = 0.f;
#pragma unroll
        for (int k = 0; k < 16; ++k) { S1 += r1[k][t]; S2 += r2[k][t]; }
        const float g = gamma[0];
        const float invN = 1.f / 16384.f;       // B*SY
        const float mean = S1 * invN;
        const float var  = S2 * invN - mean * mean;
        const float inv  = rsqrtf(g * g * var + 1e-5f);
        const float scale = g * inv * bn_w[t];
        sc[t] = scale;
        sh[t] = bn_b[t] - mean * scale;
    }
}

// ---------------------------------------------------------------------------
// K5: epilogue.  out[b][c][4jj..4jj+3] = x + O[b][c][jj]*scale[c] + shift[c]
// ---------------------------------------------------------------------------
__global__ __launch_bounds__(256) void k_out(
    const float* __restrict__ x, const float* __restrict__ Obuf,
    const float* __restrict__ sc, const float* __restrict__ sh,
    float* __restrict__ out)
{
    const int gid = blockIdx.x * 256 + threadIdx.x;   // 0 .. B*CX*SY-1
    const int c = (gid >> 11) & 63;
    const float o  = Obuf[gid];
    const float4 xv = reinterpret_cast<const float4*>(x)[gid];
    const float val = o * sc[c] + sh[c];
    float4 r;
    r.x = xv.x + val; r.y = xv.y + val; r.z = xv.z + val; r.w = xv.w + val;
    reinterpret_cast<float4*>(out)[gid] = r;
}

extern "C" void kernel_launch(void* const* d_in, const int* in_sizes, int n_in,
                              void* d_out, int out_size, void* d_ws, size_t ws_size,
                              hipStream_t stream)
{
    (void)in_sizes; (void)n_in; (void)out_size; (void)ws_size;
    const float* x  = (const float*)d_in[0];
    const float* y  = (const float*)d_in[1];
    const float* wq = (const float*)d_in[2];
    const float* bq = (const float*)d_in[3];
    const float* wk = (const float*)d_in[4];
    const float* bk = (const float*)d_in[5];
    const float* wv = (const float*)d_in[6];
    const float* bv = (const float*)d_in[7];
    const float* gm = (const float*)d_in[8];
    const float* bw = (const float*)d_in[9];
    const float* bb = (const float*)d_in[10];

    char* ws = (char*)d_ws;
    ushort_t* qT  = (ushort_t*)(ws + OFF_Q);
    ushort_t* kT  = (ushort_t*)(ws + OFF_K);
    ushort_t* vBp = (ushort_t*)(ws + OFF_V);
    float*    Ob  = (float*)(ws + OFF_O);
    float*    p1  = (float*)(ws + OFF_P1);
    float*    p2  = (float*)(ws + OFF_P2);
    float*    scp = (float*)(ws + OFF_SC);
    float*    shp = (float*)(ws + OFF_SH);

    k_qk  <<<256, 1024, 0, stream>>>(y, wq, bq, wk, bk, qT, kT);
    k_v   <<<256, 1024, 0, stream>>>(x, wv, bv, vBp);
    k_attn<<<256, 1024, 0, stream>>>(qT, kT, vBp, Ob, p1, p2);
    k_bn  <<<1,   1024, 0, stream>>>(p1, p2, gm, bw, bb, scp, shp);
    k_out <<<4096, 256, 0, stream>>>(x, Ob, scp, shp, (float*)d_out);
}